// Round 12
// baseline (69.466 us; speedup 1.0000x reference)
//
#include <hip/hip_runtime.h>
#include <stdint.h>
#include <math.h>

#define NBOX 18
#define BB 512
#define DD 2048
#define NOBJ 16
#define KK 3
#define NCLS 174
#define NCAT 321
#define NQ 4
#define NPART 16  /* per-wave partials per b: 4 race blocks x 4 waves */

// ---------------- threefry2x32 (JAX-exact, 20 rounds) ----------------
__host__ __device__ __forceinline__ uint32_t rotl32(uint32_t x, int d) {
  return (x << d) | (x >> (32 - d));
}

__host__ __device__ __forceinline__ void threefry2x32(uint32_t k0, uint32_t k1,
                                                      uint32_t x0, uint32_t x1,
                                                      uint32_t& o0, uint32_t& o1) {
  uint32_t ks2 = k0 ^ k1 ^ 0x1BD11BDAu;
  x0 += k0; x1 += k1;
#define TFR(r) x0 += x1; x1 = rotl32(x1, r); x1 ^= x0;
#define R4A TFR(13) TFR(15) TFR(26) TFR(6)
#define R4B TFR(17) TFR(29) TFR(16) TFR(24)
  R4A x0 += k1;  x1 += ks2 + 1u;
  R4B x0 += ks2; x1 += k0 + 2u;
  R4A x0 += k0;  x1 += k1 + 3u;
  R4B x0 += k1;  x1 += ks2 + 4u;
  R4A x0 += ks2; x1 += k0 + 5u;
#undef R4A
#undef R4B
#undef TFR
  o0 = x0; o1 = x1;
}

__device__ __forceinline__ float bits_to_unit(uint32_t bits) {
  float f = __uint_as_float((bits >> 9) | 0x3f800000u);
  return f - 1.0f;
}

// ---- K1: heterogeneous grid — even blocks stream ori, odd blocks race ----
// grid 4096; 256 threads = 4 waves; NO LDS -> 8 blocks/CU (wave-capped).
__global__ __launch_bounds__(256) void hetero_kernel(
    const float* __restrict__ obj_fea, const float* __restrict__ cooc,
    const int* __restrict__ obj_cat, const int* __restrict__ labels,
    uint32_t r1h, uint32_t r1l,
    unsigned long long* __restrict__ part, int* __restrict__ cnts,
    float* __restrict__ ori) {
  const int role = blockIdx.x & 1;
  const int idx = blockIdx.x >> 1;     // 0..2047
  const int b = idx >> 2;
  const int q = idx & 3;
  const int tid = threadIdx.x;
  const int lane = tid & 63;
  const int wid = tid >> 6;

  if (role == 0) {
    // ---- STREAM: (b, quarter q), 128 float4 cols; lane-pairs split rows 9+9
    const int col = tid >> 1;          // 0..127
    const int rh = tid & 1;            // 0: rows 0..8, 1: rows 9..17
    const float4* src = (const float4*)obj_fea +
                        (size_t)b * NBOX * 512 + (size_t)(rh * 9) * 512 + (q << 7) + col;
    float4 S = src[0];
#pragma unroll
    for (int r = 1; r < 9; ++r) {
      float4 a = src[(size_t)r * 512];
      S.x += a.x; S.y += a.y; S.z += a.z; S.w += a.w;
    }
    float4 oth;
    oth.x = __shfl_xor(S.x, 1, 64); oth.y = __shfl_xor(S.y, 1, 64);
    oth.z = __shfl_xor(S.z, 1, 64); oth.w = __shfl_xor(S.w, 1, 64);
    if (rh == 0) {
      const float i18 = 1.0f / 18.0f;
      ((float4*)ori)[(size_t)b * 512 + (q << 7) + col] =
          make_float4((S.x + oth.x) * i18, (S.y + oth.y) * i18,
                      (S.z + oth.z) * i18, (S.w + oth.w) * i18);
    }
    return;
  }

  // ---- RACE: branchless direct scan of this wave's 512 candidates.
  // argmax(g + log w) == argmax(w / -log2 u); w==0 (invalid) can never win
  // the cross-product compare, so no compaction/divergence is needed.
  const int lab = labels[b];
  const float* crow = cooc + (size_t)lab * NCAT;
  const int jwbase = (q << 11) + (wid << 9);    // wave's candidate base
  const uint32_t cbase0 = ((uint32_t)b) << 13;  // k stride = 1<<22
  const uint32_t kstep = 1u << 22;
  float bw0 = 0.f, bt0 = 1.f, bw1 = 0.f, bt1 = 1.f, bw2 = 0.f, bt2 = 1.f;
  int bj0 = 0, bj1 = 0, bj2 = 0;
#pragma unroll 2
  for (int c = 0; c < 8; ++c) {
    const int j = jwbase + (c << 6) + lane;
    const int jb = j >> 4;
    const int cat = obj_cat[jb * NBOX + 2 + (j & 15)];
    float w = crow[cat];
    w = (jb != b) ? w : 0.0f;                   // diagonal masked
    const uint32_t cc = cbase0 + (uint32_t)j;
    uint32_t x0, x1, y0, y1, z0, z1;
    threefry2x32(r1h, r1l, 0u, cc, x0, x1);
    threefry2x32(r1h, r1l, 0u, cc + kstep, y0, y1);
    threefry2x32(r1h, r1l, 0u, cc + 2u * kstep, z0, z1);
    const float t0 = -__log2f(fmaxf(bits_to_unit(x0 ^ x1), 1.1920929e-07f));
    const float t1 = -__log2f(fmaxf(bits_to_unit(y0 ^ y1), 1.1920929e-07f));
    const float t2 = -__log2f(fmaxf(bits_to_unit(z0 ^ z1), 1.1920929e-07f));
    if (w * bt0 > bw0 * t0) { bw0 = w; bt0 = t0; bj0 = j; }  // strict >: first j kept
    if (w * bt1 > bw1 * t1) { bw1 = w; bt1 = t1; bj1 = j; }
    if (w * bt2 > bw2 * t2) { bw2 = w; bt2 = t2; bj2 = j; }
  }
#pragma unroll
  for (int mm = 1; mm < 64; mm <<= 1) {
    float ow, ot; int oj;
    ow = __shfl_xor(bw0, mm, 64); ot = __shfl_xor(bt0, mm, 64); oj = __shfl_xor(bj0, mm, 64);
    { float lv = ow * bt0, rv = bw0 * ot;
      if (lv > rv || (lv == rv && oj < bj0)) { bw0 = ow; bt0 = ot; bj0 = oj; } }
    ow = __shfl_xor(bw1, mm, 64); ot = __shfl_xor(bt1, mm, 64); oj = __shfl_xor(bj1, mm, 64);
    { float lv = ow * bt1, rv = bw1 * ot;
      if (lv > rv || (lv == rv && oj < bj1)) { bw1 = ow; bt1 = ot; bj1 = oj; } }
    ow = __shfl_xor(bw2, mm, 64); ot = __shfl_xor(bt2, mm, 64); oj = __shfl_xor(bj2, mm, 64);
    { float lv = ow * bt2, rv = bw2 * ot;
      if (lv > rv || (lv == rv && oj < bj2)) { bw2 = ow; bt2 = ot; bj2 = oj; } }
  }
  if (lane == 0) {
    const int pw = (q << 2) + wid;
    const size_t pb = (size_t)b * KK * NPART;
    part[pb + 0 * NPART + pw] =
        ((unsigned long long)__float_as_uint(bw0 / bt0) << 32) | (uint32_t)(8192 - bj0);
    part[pb + 1 * NPART + pw] =
        ((unsigned long long)__float_as_uint(bw1 / bt1) << 32) | (uint32_t)(8192 - bj1);
    part[pb + 2 * NPART + pw] =
        ((unsigned long long)__float_as_uint(bw2 / bt2) << 32) | (uint32_t)(8192 - bj2);
    cnts[b * NPART + pw] = (bw0 > 0.0f) ? 1 : 0;  // any valid candidate in stripe
  }
}

// ---- K2: meta combine + mix_fea + mix_label ----
__global__ __launch_bounds__(256) void mix_kernel(
    const float* __restrict__ obj_fea, const int* __restrict__ obj_ind,
    const int* __restrict__ labels,
    const unsigned long long* __restrict__ part, const int* __restrict__ cnts,
    uint32_t r2h, uint32_t r2l, uint32_t r3bh, uint32_t r3bl,
    float* __restrict__ mixf, float* __restrict__ mixl) {
  const int bx = blockIdx.x;
  const int b = bx >> 1;
  const int h = bx & 1;
  const int tid = threadIdx.x;
  const int off = (h << 8) + tid;

  __shared__ int s_sel[KK];
  __shared__ int s_slots[KK];
  __shared__ float s_lam;
  __shared__ int s_cnt;
  __shared__ int s_any;

  if (tid < NPART) {  // lanes 0-15: parallel 16-partial max-combine + any-or
    unsigned long long p0 = part[((size_t)b * KK + 0) * NPART + tid];
    unsigned long long p1 = part[((size_t)b * KK + 1) * NPART + tid];
    unsigned long long p2 = part[((size_t)b * KK + 2) * NPART + tid];
    int ct = cnts[b * NPART + tid];
#pragma unroll
    for (int mm = 1; mm < NPART; mm <<= 1) {
      unsigned long long qq;
      qq = __shfl_xor(p0, mm, 64); if (qq > p0) p0 = qq;
      qq = __shfl_xor(p1, mm, 64); if (qq > p1) p1 = qq;
      qq = __shfl_xor(p2, mm, 64); if (qq > p2) p2 = qq;
      ct |= __shfl_xor(ct, mm, 64);
    }
    if (tid == 0) {
      s_sel[0] = 8192 - (int)(p0 & 0xFFFFFFFFull);
      s_sel[1] = 8192 - (int)(p1 & 0xFFFFFFFFull);
      s_sel[2] = 8192 - (int)(p2 & 0xFFFFFFFFull);
      s_cnt = ct;
    }
  } else if (tid < NPART + KK) {  // slots (randint lower-bits, split subkey k2)
    const int k = tid - NPART;
    uint32_t s0, s1;
    threefry2x32(r3bh, r3bl, 0u, (uint32_t)(b * KK + k), s0, s1);
    s_slots[k] = (int)((s0 ^ s1) & 15u);
  } else if (tid == NPART + KK) {
    uint32_t c0, c1;
    threefry2x32(r2h, r2l, 0u, (uint32_t)b, c0, c1);
    s_lam = bits_to_unit(c0 ^ c1);
  } else if (tid == NPART + KK + 1) {
    int any = 0;
#pragma unroll
    for (int oo = 0; oo < NOBJ; ++oo) any |= (obj_ind[b * NBOX + 2 + oo] != 0);
    s_any = any;
  }
  __syncthreads();

  const int hc = (s_cnt != 0) && s_any;
  const float l = s_lam, l1 = 1.0f - l;
  const float4* fea4 = (const float4*)obj_fea;
  float4* mixf4 = (float4*)mixf;
  if (hc) {
#pragma unroll 1
    for (int k = 0; k < KK; ++k) {
      int s = s_sel[k];
      int bi = s >> 4, bo = s & 15, sl = s_slots[k];
      float4 a = fea4[((size_t)b * NBOX + 2 + sl) * 512 + off];
      float4 ee = fea4[((size_t)bi * NBOX + 2 + bo) * 512 + off];
      float4 ov;
      ov.x = a.x * l + ee.x * l1; ov.y = a.y * l + ee.y * l1;
      ov.z = a.z * l + ee.z * l1; ov.w = a.w * l + ee.w * l1;
      mixf4[((size_t)b * KK + k) * 512 + off] = ov;
    }
  } else {
    // rare fallback: recompute mean of rows 2..17 directly
    const float4* src = fea4 + (size_t)b * NBOX * 512 + off;
    float4 S = make_float4(0.f, 0.f, 0.f, 0.f);
#pragma unroll
    for (int r = 2; r < NBOX; ++r) {
      float4 t = src[(size_t)r * 512];
      S.x += t.x; S.y += t.y; S.z += t.z; S.w += t.w;
    }
    const float i16 = 1.0f / 16.0f;
    float4 ov = make_float4(S.x * i16, S.y * i16, S.z * i16, S.w * i16);
#pragma unroll
    for (int k = 0; k < KK; ++k) mixf4[((size_t)b * KK + k) * 512 + off] = ov;
  }

  if (h == 0 && tid < NCLS) {
    int lb = labels[b];
#pragma unroll 1
    for (int k = 0; k < KK; ++k) {
      float val;
      if (hc) {
        int ls = labels[s_sel[k] >> 4];
        val = (tid == lb ? l : 0.0f) + (tid == ls ? l1 : 0.0f);
      } else {
        val = (tid == lb) ? 1.0f : 0.0f;
      }
      mixl[(size_t)(b * KK + k) * NCLS + tid] = val;
    }
  }
}

extern "C" void kernel_launch(void* const* d_in, const int* in_sizes, int n_in,
                              void* d_out, int out_size, void* d_ws, size_t ws_size,
                              hipStream_t stream) {
  (void)in_sizes; (void)n_in; (void)out_size; (void)ws_size;
  const float* obj_fea = (const float*)d_in[0];
  const float* cooc    = (const float*)d_in[1];
  const int* obj_ind   = (const int*)d_in[2];
  const int* obj_cat   = (const int*)d_in[3];
  const int* labels    = (const int*)d_in[4];

  float* out  = (float*)d_out;
  float* ori  = out;                              // 512*2048
  float* mixf = out + (size_t)BB * DD;            // 512*3*2048
  float* mixl = mixf + (size_t)BB * KK * DD;      // 512*3*174

  char* ws = (char*)d_ws;
  unsigned long long* part = (unsigned long long*)ws;        // 512*3*16*8 = 192 KB
  int* cnts = (int*)(ws + (size_t)BB * KK * NPART * 8);      // 512*16*4  =  32 KB

  // key(42) -> split 3 (partitionable/fold-like): r_i = threefry(key,(0,i))
  uint32_t r1h, r1l, r2h, r2l, r3h, r3l;
  threefry2x32(0u, 42u, 0u, 0u, r1h, r1l);
  threefry2x32(0u, 42u, 0u, 1u, r2h, r2l);
  threefry2x32(0u, 42u, 0u, 2u, r3h, r3l);
  // randint(r3,...) splits internally: k1,k2 = split(r3); lower_bits uses k2
  uint32_t r3bh, r3bl;
  threefry2x32(r3h, r3l, 0u, 1u, r3bh, r3bl);

  hipLaunchKernelGGL(hetero_kernel, dim3(BB * NQ * 2), dim3(256), 0, stream,
                     obj_fea, cooc, obj_cat, labels, r1h, r1l,
                     part, cnts, ori);
  hipLaunchKernelGGL(mix_kernel, dim3(BB * 2), dim3(256), 0, stream,
                     obj_fea, obj_ind, labels, part, cnts,
                     r2h, r2l, r3bh, r3bl, mixf, mixl);
}

// Round 13
// 48.438 us; speedup vs baseline: 1.4341x; 1.4341x over previous
//
#include <hip/hip_runtime.h>
#include <stdint.h>
#include <math.h>

#define NBOX 18
#define BB 512
#define DD 2048
#define NOBJ 16
#define KK 3
#define NCLS 174
#define NCAT 321

// ---------------- threefry2x32 (JAX-exact, 20 rounds) ----------------
__host__ __device__ __forceinline__ uint32_t rotl32(uint32_t x, int d) {
  return (x << d) | (x >> (32 - d));
}

__host__ __device__ __forceinline__ void threefry2x32(uint32_t k0, uint32_t k1,
                                                      uint32_t x0, uint32_t x1,
                                                      uint32_t& o0, uint32_t& o1) {
  uint32_t ks2 = k0 ^ k1 ^ 0x1BD11BDAu;
  x0 += k0; x1 += k1;
#define TFR(r) x0 += x1; x1 = rotl32(x1, r); x1 ^= x0;
#define R4A TFR(13) TFR(15) TFR(26) TFR(6)
#define R4B TFR(17) TFR(29) TFR(16) TFR(24)
  R4A x0 += k1;  x1 += ks2 + 1u;
  R4B x0 += ks2; x1 += k0 + 2u;
  R4A x0 += k0;  x1 += k1 + 3u;
  R4B x0 += k1;  x1 += ks2 + 4u;
  R4A x0 += ks2; x1 += k0 + 5u;
#undef R4A
#undef R4B
#undef TFR
  o0 = x0; o1 = x1;
}

__device__ __forceinline__ float bits_to_unit(uint32_t bits) {
  float f = __uint_as_float((bits >> 9) | 0x3f800000u);
  return f - 1.0f;
}

// ---- K1: wave-heterogeneous — waves 0-5 race, waves 6-7 stream ori ----
// grid 1024 = (b, half h); 512 threads = 8 waves; no LDS, no barriers.
// Racer density = 24 waves/CU (r2's proven shape: 32-iteration loops).
__global__ __launch_bounds__(512, 8) void k1_race_stream(
    const float* __restrict__ obj_fea, const float* __restrict__ cooc,
    const int* __restrict__ obj_cat, const int* __restrict__ labels,
    uint32_t r1h, uint32_t r1l,
    unsigned long long* __restrict__ part, int* __restrict__ cnts,
    float* __restrict__ ori) {
  const int bid = blockIdx.x;
  const int b = bid >> 1;
  const int h = bid & 1;
  const int tid = threadIdx.x;
  const int lane = tid & 63;
  const int wid = tid >> 6;

  if (wid >= 6) {
    // ---- STREAM role: 2 waves cover this half's 256 float4 cols, 2 cols/thread
    const int col = (h << 8) + ((wid - 6) << 6) + lane;  // and col+128
    const float4* src = (const float4*)obj_fea + (size_t)b * NBOX * 512;
    float4 s0 = src[col];
    float4 s1 = src[col + 128];
#pragma unroll
    for (int r = 1; r < NBOX; ++r) {
      float4 a = src[(size_t)r * 512 + col];
      float4 c = src[(size_t)r * 512 + col + 128];
      s0.x += a.x; s0.y += a.y; s0.z += a.z; s0.w += a.w;
      s1.x += c.x; s1.y += c.y; s1.z += c.z; s1.w += c.w;
    }
    const float i18 = 1.0f / 18.0f;
    float4* o4 = (float4*)ori + (size_t)b * 512;
    o4[col]       = make_float4(s0.x * i18, s0.y * i18, s0.z * i18, s0.w * i18);
    o4[col + 128] = make_float4(s1.x * i18, s1.y * i18, s1.z * i18, s1.w * i18);
    return;
  }

  // ---- RACE role: wave (k = wid>>1, sub = wid&1) scans 2048 candidates,
  // 32 iterations/lane. argmax(g+log w) == argmax(w / -log2 u); w==0 never wins.
  const int k = wid >> 1;
  const int sub = wid & 1;
  const int lab = labels[b];
  const float* crow = cooc + (size_t)lab * NCAT;
  const int jwbase = (h << 12) + (sub << 11);
  const uint32_t cbase = ((uint32_t)k << 22) + ((uint32_t)b << 13);
  float bw = 0.f, bt = 1.f;
  int bj = 0;
#pragma unroll 2
  for (int c = 0; c < 32; ++c) {
    const int j = jwbase + (c << 6) + lane;
    const int jb = j >> 4;
    const int cat = obj_cat[jb * NBOX + 2 + (j & 15)];
    float w = crow[cat];
    w = (jb != b) ? w : 0.0f;                   // diagonal masked
    uint32_t x0, x1;
    threefry2x32(r1h, r1l, 0u, cbase + (uint32_t)j, x0, x1);
    const float t = -__log2f(fmaxf(bits_to_unit(x0 ^ x1), 1.1920929e-07f));
    if (w * bt > bw * t) { bw = w; bt = t; bj = j; }  // strict >: first j kept
  }
#pragma unroll
  for (int mm = 1; mm < 64; mm <<= 1) {
    const float ow = __shfl_xor(bw, mm, 64);
    const float ot = __shfl_xor(bt, mm, 64);
    const int oj = __shfl_xor(bj, mm, 64);
    const float lv = ow * bt, rv = bw * ot;
    if (lv > rv || (lv == rv && oj < bj)) { bw = ow; bt = ot; bj = oj; }
  }
  if (lane == 0) {
    const int p = (h << 1) + sub;  // stripe index 0..3
    part[((size_t)b * KK + k) * 4 + p] =
        ((unsigned long long)__float_as_uint(bw / bt) << 32) | (uint32_t)(8192 - bj);
    if (k == 0) cnts[b * 4 + p] = (bw > 0.0f) ? 1 : 0;  // k=0 stripes cover all j
  }
}

// ---- K2: meta combine + mix_fea + mix_label ----
__global__ __launch_bounds__(256) void mix_kernel(
    const float* __restrict__ obj_fea, const int* __restrict__ obj_ind,
    const int* __restrict__ labels,
    const unsigned long long* __restrict__ part, const int* __restrict__ cnts,
    uint32_t r2h, uint32_t r2l, uint32_t r3bh, uint32_t r3bl,
    float* __restrict__ mixf, float* __restrict__ mixl) {
  const int bx = blockIdx.x;
  const int b = bx >> 1;
  const int h = bx & 1;
  const int tid = threadIdx.x;
  const int off = (h << 8) + tid;

  __shared__ int s_sel[KK];
  __shared__ int s_slots[KK];
  __shared__ float s_lam;
  __shared__ int s_hcflag;

  if (tid < 12) {  // lanes 0-11: quad-reduce the 4 stripe partials per k
    const int k = tid >> 2, p = tid & 3;
    unsigned long long v = part[((size_t)b * KK + k) * 4 + p];
    unsigned long long q;
    q = __shfl_xor(v, 1, 64); if (q > v) v = q;
    q = __shfl_xor(v, 2, 64); if (q > v) v = q;
    if (p == 0) s_sel[k] = 8192 - (int)(v & 0xFFFFFFFFull);
  } else if (tid == 12) {
    int ct = cnts[b * 4] | cnts[b * 4 + 1] | cnts[b * 4 + 2] | cnts[b * 4 + 3];
    int any = 0;
#pragma unroll
    for (int oo = 0; oo < NOBJ; ++oo) any |= (obj_ind[b * NBOX + 2 + oo] != 0);
    s_hcflag = ct && any;
  } else if (tid < 16 + KK && tid >= 16) {  // slots (randint lower-bits, subkey k2)
    const int k = tid - 16;
    uint32_t s0, s1;
    threefry2x32(r3bh, r3bl, 0u, (uint32_t)(b * KK + k), s0, s1);
    s_slots[k] = (int)((s0 ^ s1) & 15u);
  } else if (tid == 19) {
    uint32_t c0, c1;
    threefry2x32(r2h, r2l, 0u, (uint32_t)b, c0, c1);
    s_lam = bits_to_unit(c0 ^ c1);
  }
  __syncthreads();

  const int hc = s_hcflag;
  const float l = s_lam, l1 = 1.0f - l;
  const float4* fea4 = (const float4*)obj_fea;
  float4* mixf4 = (float4*)mixf;
  if (hc) {
#pragma unroll 1
    for (int k = 0; k < KK; ++k) {
      int s = s_sel[k];
      int bi = s >> 4, bo = s & 15, sl = s_slots[k];
      float4 a = fea4[((size_t)b * NBOX + 2 + sl) * 512 + off];
      float4 ee = fea4[((size_t)bi * NBOX + 2 + bo) * 512 + off];
      float4 ov;
      ov.x = a.x * l + ee.x * l1; ov.y = a.y * l + ee.y * l1;
      ov.z = a.z * l + ee.z * l1; ov.w = a.w * l + ee.w * l1;
      mixf4[((size_t)b * KK + k) * 512 + off] = ov;
    }
  } else {
    // rare fallback: recompute mean of rows 2..17 directly
    const float4* src = fea4 + (size_t)b * NBOX * 512 + off;
    float4 S = make_float4(0.f, 0.f, 0.f, 0.f);
#pragma unroll
    for (int r = 2; r < NBOX; ++r) {
      float4 t = src[(size_t)r * 512];
      S.x += t.x; S.y += t.y; S.z += t.z; S.w += t.w;
    }
    const float i16 = 1.0f / 16.0f;
    float4 ov = make_float4(S.x * i16, S.y * i16, S.z * i16, S.w * i16);
#pragma unroll
    for (int k = 0; k < KK; ++k) mixf4[((size_t)b * KK + k) * 512 + off] = ov;
  }

  if (h == 0 && tid < NCLS) {
    int lb = labels[b];
#pragma unroll 1
    for (int k = 0; k < KK; ++k) {
      float val;
      if (hc) {
        int ls = labels[s_sel[k] >> 4];
        val = (tid == lb ? l : 0.0f) + (tid == ls ? l1 : 0.0f);
      } else {
        val = (tid == lb) ? 1.0f : 0.0f;
      }
      mixl[(size_t)(b * KK + k) * NCLS + tid] = val;
    }
  }
}

extern "C" void kernel_launch(void* const* d_in, const int* in_sizes, int n_in,
                              void* d_out, int out_size, void* d_ws, size_t ws_size,
                              hipStream_t stream) {
  (void)in_sizes; (void)n_in; (void)out_size; (void)ws_size;
  const float* obj_fea = (const float*)d_in[0];
  const float* cooc    = (const float*)d_in[1];
  const int* obj_ind   = (const int*)d_in[2];
  const int* obj_cat   = (const int*)d_in[3];
  const int* labels    = (const int*)d_in[4];

  float* out  = (float*)d_out;
  float* ori  = out;                              // 512*2048
  float* mixf = out + (size_t)BB * DD;            // 512*3*2048
  float* mixl = mixf + (size_t)BB * KK * DD;      // 512*3*174

  char* ws = (char*)d_ws;
  unsigned long long* part = (unsigned long long*)ws;   // 512*3*4*8 = 48 KB
  int* cnts = (int*)(ws + (size_t)BB * KK * 4 * 8);     // 512*4*4   =  8 KB

  // key(42) -> split 3 (partitionable/fold-like): r_i = threefry(key,(0,i))
  uint32_t r1h, r1l, r2h, r2l, r3h, r3l;
  threefry2x32(0u, 42u, 0u, 0u, r1h, r1l);
  threefry2x32(0u, 42u, 0u, 1u, r2h, r2l);
  threefry2x32(0u, 42u, 0u, 2u, r3h, r3l);
  // randint(r3,...) splits internally: k1,k2 = split(r3); lower_bits uses k2
  uint32_t r3bh, r3bl;
  threefry2x32(r3h, r3l, 0u, 1u, r3bh, r3bl);

  hipLaunchKernelGGL(k1_race_stream, dim3(BB * 2), dim3(512), 0, stream,
                     obj_fea, cooc, obj_cat, labels, r1h, r1l,
                     part, cnts, ori);
  hipLaunchKernelGGL(mix_kernel, dim3(BB * 2), dim3(256), 0, stream,
                     obj_fea, obj_ind, labels, part, cnts,
                     r2h, r2l, r3bh, r3bl, mixf, mixl);
}